// Round 8
// baseline (159.608 us; speedup 1.0000x reference)
//
#include <hip/hip_runtime.h>
#include <cstdint>

// Hierarchical classification head, R16 (= R8 tail + barrier-free GEMM):
//   cast         : fp32 -> fp8 e4m3 X and W (W pre-scaled x16), bias fp32
//   gemm_sig     : Zb = sigmoid((Xq @ Wq^T)/16 + b) bf16; fp8 MFMA 16x16x32.
//                  NEW (R16): ZERO BARRIERS. Each wave owns a private 12 KB
//                  LDS slice (A 32x64 + B 64x64, double-buffered) and stages
//                  its own fragments with global_load_lds + per-wave counted
//                  vmcnt(6). Rationale: R8(drain)/R11(dbuf)/R13(counted) all
//                  ~41-43 us with NO pipe >25% busy -- the block barrier
//                  convoys all 4 waves twice per 16-MFMA iter, so stalls
//                  synchronize instead of interleaving. vmcnt is per-wave
//                  state -> waves drift freely, 12 waves/CU hide L2 latency.
//                  Cost: A/B staged 2x per block (L2 ~20 TB/s < 34.5 ceiling),
//                  LDS 48 KB -> 3 blocks/CU. Same 16B-rotation swizzle and
//                  XCD band swizzle (1600 blocks) as R13.
//                  R15 post-mortem: 128^2 tile = 54 us (800 blocks = 3.1/CU
//                  grid-limited, occ 18.7% -- R7's mistake rediscovered).
//   logits_loss  : per-row logits3 -> d_out; 588 ancestor z in LDS, z3[k]
//                  streamed (R8, measured ~14 us).
//   final_reduce : 4096 partials -> mean loss (separate launch; cross-XCD
//                  fence schemes cost 400 us -- R14 lesson).

typedef unsigned short u16;
typedef unsigned char u8;
typedef long i64;
typedef float f32x4 __attribute__((ext_vector_type(4)));

#define AS_G __attribute__((address_space(1)))
#define AS_L __attribute__((address_space(3)))

constexpr int BATCH = 4096;
constexpr int H     = 1024;
constexpr int N1 = 28, N2 = 280, N3 = 2800;
constexpr int NT = N1 + N2 + N3;   // 3108
constexpr int NP = 3200;           // 25 * 128
constexpr int NANC = N1 + N2 + 280;  // 588 ancestor values
constexpr float WSCALE = 16.0f;
constexpr float WINV   = 1.0f / 16.0f;

__device__ inline u16 f2bf(float f) {
    unsigned int u = __float_as_uint(f);
    u += 0x7fffu + ((u >> 16) & 1u);
    return (u16)(u >> 16);
}
__device__ inline float bf2f(unsigned int u) { return __uint_as_float(u << 16); }

__device__ inline unsigned int pk4_fp8(float a, float b, float c, float d) {
    unsigned int r = __builtin_amdgcn_cvt_pk_fp8_f32(a, b, 0, false);
    r = __builtin_amdgcn_cvt_pk_fp8_f32(c, d, (int)r, true);
    return r;
}

// ---------------- cast fp32 -> fp8 + fused bias ----------------
constexpr int XG = (BATCH * H) / 4;   // 1,048,576
constexpr int WG = (NP * H) / 4;      //   819,200
constexpr int BG = NP / 4;            //       800

__global__ __launch_bounds__(256) void cast_kernel(
        const float* __restrict__ x,
        const float* __restrict__ W1, const float* __restrict__ W2,
        const float* __restrict__ W3,
        const float* __restrict__ b1, const float* __restrict__ b2,
        const float* __restrict__ b3,
        u8* __restrict__ Xq, u8* __restrict__ Wq, float* __restrict__ biasf) {
    int g = blockIdx.x * 256 + threadIdx.x;
    if (g < XG) {
        float4 v = ((const float4*)x)[g];
        ((unsigned int*)Xq)[g] = pk4_fp8(v.x, v.y, v.z, v.w);
    } else if (g < XG + WG) {
        int wg = g - XG;
        int row = wg >> 8, cg = wg & 255;
        float4 v = make_float4(0.f, 0.f, 0.f, 0.f);
        if (row < N1)           v = ((const float4*)W1)[row * 256 + cg];
        else if (row < N1 + N2) v = ((const float4*)W2)[(row - N1) * 256 + cg];
        else if (row < NT)      v = ((const float4*)W3)[(row - N1 - N2) * 256 + cg];
        ((unsigned int*)Wq)[wg] = pk4_fp8(v.x * WSCALE, v.y * WSCALE, v.z * WSCALE, v.w * WSCALE);
    } else if (g < XG + WG + BG) {
        int bg = g - XG - WG;
        float4 v; float* vp = &v.x;
        #pragma unroll
        for (int i = 0; i < 4; ++i) {
            int c = bg * 4 + i; float t = 0.f;
            if (c < N1)           t = b1[c];
            else if (c < N1 + N2) t = b2[c - N1];
            else if (c < NT)      t = b3[c - N1 - N2];
            vp[i] = t;
        }
        ((float4*)biasf)[bg] = v;
    }
}

// ---------------- GEMM: Zb = sigmoid(acc/16 + bias), fp8 inputs, bf16 out ----------------
// 64x128 block tile, 4 waves 2x2 (wave = 32 rows x 64 cols), BK=64.
// Per-wave private LDS: [wave][buf][A 2KB | B 4KB]; 48 KB total.
// Zero barriers; per-wave counted vmcnt(6); 1600 blocks.
__global__ __launch_bounds__(256) void gemm_sig(
        const u8* __restrict__ Xq, const u8* __restrict__ Wq,
        const float* __restrict__ biasf, u16* __restrict__ Zb) {
    __shared__ __align__(16) u8 lds[4][2][6144];   // 48 KB

    // XCD band swizzle: 64 m-tiles x 25 n-tiles; XCD owns an 8-m-tile band.
    const int id  = blockIdx.x;        // 0..1599
    const int xcd = id & 7;
    const int j   = id >> 3;           // 0..199
    const int m0 = ((xcd << 3) | (j & 7)) * 64;    // m-tile 0..63
    const int n0 = (j >> 3) * 128;                 // n-tile 0..24

    const int tid  = threadIdx.x;
    const int lane = tid & 63;
    const int wave = tid >> 6;
    const int wr = wave >> 1;          // m half (32 rows)
    const int wc = wave & 1;           // n half (64 cols)

    const int laneM = lane & 15;
    // 16B-rotation swizzle (R7): unit index = (u>>1) ^ ((row>>2)&1)
    const int u   = lane >> 4;
    const int xb  = (laneM >> 2) & 1;
    const int laneKb = (((u >> 1) ^ xb) << 4) + (u & 1) * 8;

    // per-wave staging geometry: A 128 chunks (2/lane), B 256 chunks (4/lane).
    // A layout [panel2][row32][32B]; B layout [panel2][row64][32B] after A's 2KB.
    const int srow = lane >> 1;        // 0..31
    const int sv   = lane & 1;
    const int sgA  = (sv ^ ((srow >> 2) & 1)) << 4;   // swizzled 16B unit

    u8* wb[2] = { &lds[wave][0][0], &lds[wave][1][0] };
    const u8* Arow0 = Xq + (size_t)(m0 + wr * 32) * H;
    const u8* Brow0 = Wq + (size_t)(n0 + wc * 64) * H;

    auto STAGE = [&](u8* base, int kt) {       // 6 global_load_lds / lane
        const int k0 = kt * 64;
        #pragma unroll
        for (int q2 = 0; q2 < 2; ++q2) {       // A: 2 loads
            __builtin_amdgcn_global_load_lds(
                (const AS_G uint32_t*)(Arow0 + (size_t)srow * H + k0 + q2 * 32 + sgA),
                (AS_L uint32_t*)(base + (lane + 64 * q2) * 16), 16, 0, 0);
        }
        #pragma unroll
        for (int q = 0; q < 4; ++q) {          // B: 4 loads
            const int row = (lane + 64 * (q & 1)) >> 1;         // 0..63
            const int goff = (q >> 1) * 32 + ((sv ^ ((row >> 2) & 1)) << 4);
            __builtin_amdgcn_global_load_lds(
                (const AS_G uint32_t*)(Brow0 + (size_t)row * H + k0 + goff),
                (AS_L uint32_t*)(base + 2048 + (lane + 64 * q) * 16), 16, 0, 0);
        }
    };

    f32x4 acc[2][4] = {};

    STAGE(wb[0], 0);
    int buf = 0;
    for (int kt = 0; kt < H / 64; ++kt) {          // 16 iterations, no barriers
        if (kt + 1 < H / 64) {
            STAGE(wb[buf ^ 1], kt + 1);            // next tile: stays in flight
            asm volatile("s_waitcnt vmcnt(6)" ::: "memory");   // cur tile landed
        } else {
            asm volatile("s_waitcnt vmcnt(0)" ::: "memory");
        }
        __builtin_amdgcn_sched_barrier(0);         // pin ds_reads below (rule #18)

        const u8* base = wb[buf];
        #pragma unroll
        for (int p = 0; p < 2; ++p) {               // 2 k-panels of 32
            i64 af[2], bfv[4];
            #pragma unroll
            for (int i = 0; i < 2; ++i)
                af[i]  = *(const i64*)(base + p * 1024 + (i * 16 + laneM) * 32 + laneKb);
            #pragma unroll
            for (int i = 0; i < 4; ++i)
                bfv[i] = *(const i64*)(base + 2048 + p * 2048 + (i * 16 + laneM) * 32 + laneKb);
            #pragma unroll
            for (int am = 0; am < 2; ++am)
                #pragma unroll
                for (int bn = 0; bn < 4; ++bn)
                    acc[am][bn] = __builtin_amdgcn_mfma_f32_16x16x32_fp8_fp8(
                        af[am], bfv[bn], acc[am][bn], 0, 0, 0);
        }
        __builtin_amdgcn_sched_barrier(0);         // keep iteration order
        buf ^= 1;
    }

    // epilogue: C/D layout col = lane&15, row = (lane>>4)*4 + r; unscale, bf16 store
    #pragma unroll
    for (int bn = 0; bn < 4; ++bn) {
        const int col = n0 + wc * 64 + bn * 16 + laneM;
        if (col >= NT) continue;
        const float bias = biasf[col];
        #pragma unroll
        for (int am = 0; am < 2; ++am) {
            const int rbase = m0 + wr * 32 + am * 16 + u * 4;
            #pragma unroll
            for (int r = 0; r < 4; ++r) {
                float v = acc[am][bn][r] * WINV + bias;
                Zb[(size_t)(rbase + r) * NP + col] = f2bf(1.0f / (1.0f + __expf(-v)));
            }
        }
    }
}

// ---------------- per-row logits + CE partial (no atomic, no fence) ----------------
// LDS holds only the 588 ancestor z (z1|z2|z3[0:280)); z3[k] streamed global.
__global__ __launch_bounds__(256) void logits_loss(
        const u16* __restrict__ Zb, const int* __restrict__ labels,
        float* __restrict__ out, float* __restrict__ partials) {
    __shared__ float zs[NANC];             // [0,28) z1 | [28,308) z2 | [308,588) z3[0:280)
    __shared__ float red[12];
    const int b = blockIdx.x, tid = threadIdx.x;
    const u16* Zrow = Zb + (size_t)b * NP;

    const unsigned int* Zr = (const unsigned int*)Zrow;
    for (int i = tid; i < NANC / 2; i += 256) {    // 294 uints
        unsigned int v = Zr[i];
        zs[2 * i]     = bf2f(v & 0xffffu);
        zs[2 * i + 1] = bf2f(v >> 16);
    }
    __syncthreads();

    float se1 = 0.f, se2 = 0.f, se3 = 0.f;
    float4* outr4 = (float4*)(out + (size_t)b * N3);
    // z3 block starts at element 308 (uint index 154, even -> uint2-aligned)
    const uint2* Z3s = (const uint2*)(Zrow + N1 + N2);
    for (int q = tid; q < N3 / 4; q += 256) {
        const uint2 zv = Z3s[q];               // z3[4q..4q+3]
        float z3v[4] = { bf2f(zv.x & 0xffffu), bf2f(zv.x >> 16),
                         bf2f(zv.y & 0xffffu), bf2f(zv.y >> 16) };
        const int k = q * 4;
        float4 o; float* op = &o.x;
        #pragma unroll
        for (int uu = 0; uu < 4; ++uu) {
            const int kk = k + uu;
            float lg = z3v[uu] * zs[308 + kk / 10] * zs[308 + kk / 100];
            op[uu] = lg;
            se3 += __expf(lg);
        }
        outr4[q] = o;
    }
    for (int jj = tid; jj < N2; jj += 256)
        se2 += __expf(zs[N1 + jj] * zs[N1 + jj / 10]);
    if (tid < N1)
        se1 = __expf(zs[tid]);

    #pragma unroll
    for (int off = 32; off > 0; off >>= 1) {
        se1 += __shfl_down(se1, off, 64);
        se2 += __shfl_down(se2, off, 64);
        se3 += __shfl_down(se3, off, 64);
    }
    if ((tid & 63) == 0) {
        int w = tid >> 6;
        red[w] = se3; red[4 + w] = se2; red[8 + w] = se1;
    }
    __syncthreads();
    if (tid == 0) {
        float s3 = red[0] + red[1] + red[2] + red[3];
        float s2 = red[4] + red[5] + red[6] + red[7];
        float s1 = red[8] + red[9] + red[10] + red[11];
        int lab  = labels[b];
        int lab2 = lab / 10, lab1 = lab / 100;
        float l1 = zs[lab1];
        float l2 = zs[N1 + lab2] * zs[N1 + lab2 / 10];
        float l3 = bf2f((unsigned int)Zrow[N1 + N2 + lab]) * zs[308 + lab2] * zs[308 + lab1];
        partials[b] = (logf(s1) - l1) + (logf(s2) - l2) + (logf(s3) - l3);
    }
}

// ---------------- final loss reduce ----------------
__global__ __launch_bounds__(256) void final_reduce(
        const float* __restrict__ partials, float* __restrict__ out) {
    __shared__ float red[4];
    const int tid = threadIdx.x;
    float s = 0.f;
    for (int i = tid; i < BATCH; i += 256) s += partials[i];
    #pragma unroll
    for (int off = 32; off > 0; off >>= 1) s += __shfl_down(s, off, 64);
    if ((tid & 63) == 0) red[tid >> 6] = s;
    __syncthreads();
    if (tid == 0)
        out[(size_t)BATCH * N3] = (red[0] + red[1] + red[2] + red[3]) * (1.0f / BATCH);
}

extern "C" void kernel_launch(void* const* d_in, const int* in_sizes, int n_in,
                              void* d_out, int out_size, void* d_ws, size_t ws_size,
                              hipStream_t stream) {
    const float* x      = (const float*)d_in[0];
    const int*   labels = (const int*)d_in[1];
    const float* W1     = (const float*)d_in[2];
    const float* b1     = (const float*)d_in[3];
    const float* W2     = (const float*)d_in[4];
    const float* b2     = (const float*)d_in[5];
    const float* W3     = (const float*)d_in[6];
    const float* b3     = (const float*)d_in[7];
    float* out = (float*)d_out;

    char* ws = (char*)d_ws;
    u8*    Xq       = (u8*)ws;                     //  4,194,304 B  [4096][1024] fp8
    u8*    Wq       = (u8*)(ws + 4194304);         //  3,276,800 B  [3200][1024] fp8
    u16*   Zb       = (u16*)(ws + 7471104);        // 26,214,400 B  [4096][3200] bf16
    float* biasf    = (float*)(ws + 33685504);     //     12,800 B
    float* partials = (float*)(ws + 33698304);     //     16,384 B
    // total ws use: 33,714,688 B

    cast_kernel<<<(XG + WG + BG + 255) / 256, 256, 0, stream>>>(
        x, W1, W2, W3, b1, b2, b3, Xq, Wq, biasf);
    gemm_sig<<<1600, 256, 0, stream>>>(Xq, Wq, biasf, Zb);
    logits_loss<<<BATCH, 256, 0, stream>>>(Zb, labels, out, partials);
    final_reduce<<<1, 256, 0, stream>>>(partials, out);
}